// Round 6
// baseline (310.663 us; speedup 1.0000x reference)
//
#include <hip/hip_runtime.h>

// Smallfry decode: out[b,s,:] = concat_{blk<128} codebook[codes[input_ids[b,s], blk], :4]
// input_ids [32,4096] i32, codes [100000,128] i32, codebook [256,4] f32,
// out [32,4096,512] f32 (= [NTOK,128] float4).
//
// R5 post-mortem: kernel ~74us of dur_us=304; harness fills/restores ~230us.
// This round: A/B the nontemporal store flag (only change vs R5).

#define NUM_BLOCKS 128
#define NUM_CODES  256
#define NTOK       (32 * 4096)
#define TOK_PER_WAVE 16

typedef float f32x4 __attribute__((ext_vector_type(4)));

__global__ __launch_bounds__(256, 8) void smallfry_decode_kernel(
    const int* __restrict__ input_ids,
    const int* __restrict__ codes,
    const f32x4* __restrict__ codebook,
    f32x4* __restrict__ out)
{
    __shared__ f32x4 cb[NUM_CODES];        // 4 KiB codebook in LDS
    if (threadIdx.x < NUM_CODES) {
        cb[threadIdx.x] = codebook[threadIdx.x];
    }
    __syncthreads();

    const int gtid = blockIdx.x * blockDim.x + threadIdx.x;
    const int lane = gtid & 63;
    const int wave = gtid >> 6;            // 8192 waves, one 16-token group each
    const int base = wave * TOK_PER_WAVE;  // exactly covers NTOK = 8192*16

    // One coalesced load fetches all 16 token ids for this wave (lanes 0..15).
    int tok_id = 0;
    if (lane < TOK_PER_WAVE) tok_id = input_ids[base + lane];

    // Two phases of 8 tokens, fully unrolled: 16 code loads issued back-to-back,
    // then LDS lookups + contiguous plain (non-NT) stores.
#pragma unroll
    for (int g = 0; g < 2; ++g) {
        int c0[8], c1[8];
#pragma unroll
        for (int t = 0; t < 8; ++t) {
            const int row = __shfl(tok_id, g * 8 + t);   // uniform -> readlane/SGPR base
            const int* crow = codes + (long long)row * NUM_BLOCKS;
            c0[t] = crow[lane];          // coalesced 256B: blocks [0,64)
            c1[t] = crow[lane + 64];     // coalesced 256B: blocks [64,128)
        }
#pragma unroll
        for (int t = 0; t < 8; ++t) {
            const f32x4 v0 = cb[c0[t]];
            const f32x4 v1 = cb[c1[t]];
            // Each store instruction covers a fully contiguous 1 KiB of the row.
            f32x4* orow = out + (size_t)(base + g * 8 + t) * NUM_BLOCKS;
            orow[lane]      = v0;        // plain stores this round (NT dropped)
            orow[lane + 64] = v1;
        }
    }
}

extern "C" void kernel_launch(void* const* d_in, const int* in_sizes, int n_in,
                              void* d_out, int out_size, void* d_ws, size_t ws_size,
                              hipStream_t stream) {
    const int*   input_ids = (const int*)d_in[0];
    const int*   codes     = (const int*)d_in[1];
    const f32x4* codebook  = (const f32x4*)d_in[2];
    f32x4*       out       = (f32x4*)d_out;

    const int block = 256;                         // 4 waves/block
    const int grid  = (NTOK / TOK_PER_WAVE) / 4;   // 2048 blocks -> 8192 waves
    smallfry_decode_kernel<<<grid, block, 0, stream>>>(input_ids, codes, codebook, out);
}

// Round 7
// 303.700 us; speedup vs baseline: 1.0229x; 1.0229x over previous
//
#include <hip/hip_runtime.h>

// Smallfry decode: out[b,s,:] = concat_{blk<128} codebook[codes[input_ids[b,s], blk], :4]
// input_ids [32,4096] i32, codes [100000,128] i32, codebook [256,4] f32,
// out [32,4096,512] f32 (= [NTOK,128] float4).
//
// Final structure (best measured, R5 = 304.4us):
//  - one wave per 16 tokens; ids batch-loaded, broadcast via __shfl (SGPR base)
//  - code rows read as two coalesced 256B dword loads (lane, lane+64)
//  - codebook (4 KiB) staged in LDS, random b128 gather (~1.3x bank penalty, hidden)
//  - output written as fully-contiguous 1 KiB nontemporal store pairs per wave
//    (NT keeps L2 for the 51 MB codes table; A/B'd +6us vs plain in R6)
// Kernel ~74us of dur_us~304; remaining ~230us is harness poison/restore fills.

#define NUM_BLOCKS 128
#define NUM_CODES  256
#define NTOK       (32 * 4096)
#define TOK_PER_WAVE 16

typedef float f32x4 __attribute__((ext_vector_type(4)));

__global__ __launch_bounds__(256, 8) void smallfry_decode_kernel(
    const int* __restrict__ input_ids,
    const int* __restrict__ codes,
    const f32x4* __restrict__ codebook,
    f32x4* __restrict__ out)
{
    __shared__ f32x4 cb[NUM_CODES];        // 4 KiB codebook in LDS
    if (threadIdx.x < NUM_CODES) {
        cb[threadIdx.x] = codebook[threadIdx.x];
    }
    __syncthreads();

    const int gtid = blockIdx.x * blockDim.x + threadIdx.x;
    const int lane = gtid & 63;
    const int wave = gtid >> 6;            // 8192 waves, one 16-token group each
    const int base = wave * TOK_PER_WAVE;  // exactly covers NTOK = 8192*16

    // One coalesced load fetches all 16 token ids for this wave (lanes 0..15).
    int tok_id = 0;
    if (lane < TOK_PER_WAVE) tok_id = input_ids[base + lane];

    // Two phases of 8 tokens, fully unrolled: 16 code loads issued back-to-back,
    // then LDS lookups + contiguous nontemporal stores.
#pragma unroll
    for (int g = 0; g < 2; ++g) {
        int c0[8], c1[8];
#pragma unroll
        for (int t = 0; t < 8; ++t) {
            const int row = __shfl(tok_id, g * 8 + t);   // uniform -> readlane/SGPR base
            const int* crow = codes + (long long)row * NUM_BLOCKS;
            c0[t] = crow[lane];          // coalesced 256B: blocks [0,64)
            c1[t] = crow[lane + 64];     // coalesced 256B: blocks [64,128)
        }
#pragma unroll
        for (int t = 0; t < 8; ++t) {
            const f32x4 v0 = cb[c0[t]];
            const f32x4 v1 = cb[c1[t]];
            // Each store instruction covers a fully contiguous 1 KiB of the row.
            f32x4* orow = out + (size_t)(base + g * 8 + t) * NUM_BLOCKS;
            __builtin_nontemporal_store(v0, &orow[lane]);
            __builtin_nontemporal_store(v1, &orow[lane + 64]);
        }
    }
}

extern "C" void kernel_launch(void* const* d_in, const int* in_sizes, int n_in,
                              void* d_out, int out_size, void* d_ws, size_t ws_size,
                              hipStream_t stream) {
    const int*   input_ids = (const int*)d_in[0];
    const int*   codes     = (const int*)d_in[1];
    const f32x4* codebook  = (const f32x4*)d_in[2];
    f32x4*       out       = (f32x4*)d_out;

    const int block = 256;                         // 4 waves/block
    const int grid  = (NTOK / TOK_PER_WAVE) / 4;   // 2048 blocks -> 8192 waves
    smallfry_decode_kernel<<<grid, block, 0, stream>>>(input_ids, codes, codebook, out);
}